// Round 8
// baseline (1563.934 us; speedup 1.0000x reference)
//
#include <hip/hip_runtime.h>

// Neural HMM forward-algorithm NLL.  K=128, V=50257, D=H=128, B=64, T=2048.
//
//  K1 k_emis : E[v][k] = exp(tag[k]·word[v] + bias[v]) (unnormalized) + partial Z
//  K2 k_trans: A2 (Z-folded, fallback), A2p = 128*softmax rows (fp8 path),
//              piZ (fallback), piZP = 128*softmax(init) permuted, ZinvP = V/Z_j permuted
//  K3 k_gather: em[t][b][p] = bf16( E[tok[b,t]][phi^-1(p)] * V/Z ), p = phi(j)
//  K4 k_fwd_m5: barrier-free MX-FP8 recursion, TWO independent 16-batch
//     chains per wave (r7 showed 8-MFMA step = 277 pipe cyc of a 948-cyc
//     step -> ~470 cyc exposed stall; second chain fills it. r6's dual-chain
//     failure was under pipe saturation - not the case here).
//     mfma_scale_f32_16x16x128_f8f6f4: whole K=128 matvec in ONE MFMA.
//     phi: j = 16jt + 4g + r -> p = 32g + 4jt + r  makes MFMA jt's D regs
//     exactly next step's B word jt (lane-local, zero shuffles).
//     A stored x128 with e8m0 scale 2^-7; Z folded into em so alpha ~1.0.
//  K5 k_final : out = -sum_b ll[b]

#define KK 128
#define TT 2048
#define BB 64

typedef int v8i __attribute__((ext_vector_type(8)));
typedef float v4f __attribute__((ext_vector_type(4)));

__device__ __forceinline__ float wave_sum64(float v) {
#pragma unroll
  for (int m = 32; m; m >>= 1) v += __shfl_xor(v, m, 64);
  return v;
}
__device__ __forceinline__ float wave_max64(float v) {
#pragma unroll
  for (int m = 32; m; m >>= 1) v = fmaxf(v, __shfl_xor(v, m, 64));
  return v;
}
// f32 -> bf16 round-to-nearest-even (positive normals here)
__device__ __forceinline__ unsigned short f2bf(float x) {
  union { float f; unsigned u; } c; c.f = x;
  unsigned r = c.u + 0x7fffu + ((c.u >> 16) & 1u);
  return (unsigned short)(r >> 16);
}
__device__ __forceinline__ float bflo(unsigned u) {
  union { unsigned u; float f; } c; c.u = u << 16; return c.f;
}
__device__ __forceinline__ float bfhi(unsigned u) {
  union { unsigned u; float f; } c; c.u = u & 0xffff0000u; return c.f;
}

// ---------------- K1: emission table E (V x K) + partial Z ----------------
__global__ __launch_bounds__(128, 1)
void k_emis(const float* __restrict__ tag, const float* __restrict__ word,
            const float* __restrict__ bias, float* __restrict__ E,
            float* __restrict__ partialZ, int V) {
  __shared__ float4 wtile[128 * 32];
  __shared__ float btile[128];
  const int tid = threadIdx.x;
  const int v0 = blockIdx.x * 128;

  const float4* w4 = (const float4*)word;
  const int maxi = V * 32 - 1;
#pragma unroll
  for (int it = 0; it < 32; ++it) {
    int idx = it * 128 + tid;
    int g = v0 * 32 + idx;
    wtile[idx] = w4[min(g, maxi)];
  }
  btile[tid] = (v0 + tid < V) ? bias[v0 + tid] : 0.f;

  float treg[128];
  const float4* t4 = (const float4*)(tag + (size_t)tid * 128);
#pragma unroll
  for (int c = 0; c < 32; ++c) {
    float4 x = t4[c];
    treg[4 * c + 0] = x.x; treg[4 * c + 1] = x.y;
    treg[4 * c + 2] = x.z; treg[4 * c + 3] = x.w;
  }
  __syncthreads();

  float zp = 0.f;
  for (int v = 0; v < 128; ++v) {
    if (v0 + v >= V) break;  // uniform
    const float4* row = &wtile[v * 32];
    float a0 = 0.f, a1 = 0.f, a2 = 0.f, a3 = 0.f;
#pragma unroll
    for (int c = 0; c < 32; ++c) {
      float4 pv = row[c];
      a0 = fmaf(pv.x, treg[4 * c + 0], a0);
      a1 = fmaf(pv.y, treg[4 * c + 1], a1);
      a2 = fmaf(pv.z, treg[4 * c + 2], a2);
      a3 = fmaf(pv.w, treg[4 * c + 3], a3);
    }
    float e = __expf((a0 + a1) + (a2 + a3) + btile[v]);
    E[(size_t)(v0 + v) * KK + tid] = e;
    zp += e;
  }
  partialZ[(size_t)blockIdx.x * KK + tid] = zp;
}

// ---------------- K2: transition matrix + piZ/piZP/ZinvP/A2p ----------
__global__ __launch_bounds__(128)
void k_trans(const float* __restrict__ W, const float* __restrict__ q,
             const float* __restrict__ tb, const float* __restrict__ pZ,
             const float* __restrict__ initlog, float* __restrict__ A2,
             float* __restrict__ A2p, float* __restrict__ piZ,
             float* __restrict__ piZP, float* __restrict__ ZinvP,
             int nPart, int V) {
  __shared__ float qs[KK];
  __shared__ float r0[2], r1[2];
  const int j = threadIdx.x, i = blockIdx.x;
  qs[j] = q[j];
  __syncthreads();

  const float4* w4 = (const float4*)(W + ((size_t)(i * KK + j)) * KK);
  const float4* q4 = (const float4*)qs;
  float a0 = 0.f, a1 = 0.f, a2 = 0.f, a3 = 0.f;
#pragma unroll
  for (int c = 0; c < KK / 4; ++c) {
    float4 wv = w4[c], qv = q4[c];
    a0 = fmaf(wv.x, qv.x, a0); a1 = fmaf(wv.y, qv.y, a1);
    a2 = fmaf(wv.z, qv.z, a2); a3 = fmaf(wv.w, qv.w, a3);
  }
  float logit = (a0 + a1) + (a2 + a3) + tb[i * KK + j];

  float m = wave_max64(logit);
  if ((j & 63) == 0) r0[j >> 6] = m;
  __syncthreads();
  m = fmaxf(r0[0], r0[1]);
  float e = __expf(logit - m);
  float s = wave_sum64(e);
  if ((j & 63) == 0) r1[j >> 6] = s;
  __syncthreads();
  s = r1[0] + r1[1];

  float Z0 = 0.f, Z1 = 0.f, Z2 = 0.f, Z3 = 0.f;
  float Z4 = 0.f, Z5 = 0.f, Z6 = 0.f, Z7 = 0.f;
  int p = 0;
  for (; p + 8 <= nPart; p += 8) {
    Z0 += pZ[(size_t)(p + 0) * KK + j]; Z1 += pZ[(size_t)(p + 1) * KK + j];
    Z2 += pZ[(size_t)(p + 2) * KK + j]; Z3 += pZ[(size_t)(p + 3) * KK + j];
    Z4 += pZ[(size_t)(p + 4) * KK + j]; Z5 += pZ[(size_t)(p + 5) * KK + j];
    Z6 += pZ[(size_t)(p + 6) * KK + j]; Z7 += pZ[(size_t)(p + 7) * KK + j];
  }
  for (; p < nPart; ++p) Z0 += pZ[(size_t)p * KK + j];
  float Z = ((Z0 + Z1) + (Z2 + Z3)) + ((Z4 + Z5) + (Z6 + Z7));

  A2[i * KK + j] = e / (s * Z);        // fallback path (Z-folded)
  A2p[i * KK + j] = 128.0f * e / s;    // fp8 path: pure softmax x128 (~1.0)

  if (i == 0) {
    float x = initlog[j];
    __syncthreads();
    float m2 = wave_max64(x);
    if ((j & 63) == 0) r0[j >> 6] = m2;
    __syncthreads();
    m2 = fmaxf(r0[0], r0[1]);
    float e2 = __expf(x - m2);
    float s2 = wave_sum64(e2);
    if ((j & 63) == 0) r1[j >> 6] = s2;
    __syncthreads();
    s2 = r1[0] + r1[1];
    piZ[j] = e2 / (s2 * Z);
    // phi: j = 16jt + 4g + r -> p = 32g + 4jt + r
    int pp = 32 * ((j >> 2) & 3) + 4 * (j >> 4) + (j & 3);
    piZP[pp] = 128.0f * e2 / s2;
    ZinvP[pp] = (float)V / Z;
  }
}

// ---------------- K3: em gather, PERMUTED layout, Z-fold ----------------
__global__ __launch_bounds__(128, 1)
void k_gather(const int* __restrict__ toks, const float* __restrict__ E,
              const float* __restrict__ ZinvP, unsigned* __restrict__ em) {
  const int b = blockIdx.x;        // 0..63
  const int tc = blockIdx.y;       // 0..63 (32 t's each)
  const int q = threadIdx.x & 63;
  const int half = threadIdx.x >> 6;
  const int perm = 8 * ((q >> 1) & 7) + 2 * (q >> 4) + (q & 1);
  const float2 zi = ((const float2*)ZinvP)[q];
  const float2* E2 = (const float2*)E;
#pragma unroll 4
  for (int it = 0; it < 16; ++it) {
    int t = tc * 32 + it * 2 + half;
    int tok = toks[(size_t)b * TT + t];
    float2 v = E2[(size_t)tok * 64 + perm];
    unsigned lo = f2bf(v.x * zi.x), hi = f2bf(v.y * zi.y);
    em[((size_t)t * BB + b) * 64 + q] = lo | (hi << 16);
  }
}

// ---------------- K4: MX-FP8 dual-chain single-wave recursion ------------
// 2 blocks x 64 threads. lane l: m = l&15 (batch col / A col), g = l>>4.
// Chain A = batches blk*32+m, chain B = blk*32+16+m. Shared af fragments.
// af[jt] byte e: A row i = 16*(e>>2) + 4g + (e&3), col j' = 16jt + m.
// B byte e = alphaP[32g + e]; D lane (m,g) reg r = alphaP'[32g + 4jt + r].
template <int S, bool LAST>
__device__ __forceinline__ void step8d(int t,
                                       const uint4* __restrict__ emLa,
                                       const uint4* __restrict__ emLb,
                                       const v8i (&af)[8], v8i& bfa, v8i& bfb,
                                       uint4 (&emQa)[2][4], uint4 (&emQb)[2][4],
                                       float& La, float& Lb,
                                       float (&nfa)[8][4], float (&nfb)[8][4]) {
  const v4f ZED = {0.f, 0.f, 0.f, 0.f};
  const int SA = 0x78787878;  // e8m0 120 -> 2^-7 per 32-block (A stored x128)
  const int SB = 0x7f7f7f7f;  // e8m0 127 -> 1.0
  v4f acca[8], accb[8];
#pragma unroll
  for (int jt = 0; jt < 8; ++jt)
    acca[jt] = __builtin_amdgcn_mfma_scale_f32_16x16x128_f8f6f4(
        af[jt], bfa, ZED, 0, 0, 0, SA, 0, SB);
#pragma unroll
  for (int jt = 0; jt < 8; ++jt)
    accb[jt] = __builtin_amdgcn_mfma_scale_f32_16x16x128_f8f6f4(
        af[jt], bfb, ZED, 0, 0, 0, SA, 0, SB);

  uint4 eva[4], evb[4];
#pragma unroll
  for (int kc = 0; kc < 4; ++kc) { eva[kc] = emQa[S][kc]; evb[kc] = emQb[S][kc]; }
  {
    int tp = (t + 2 < TT) ? (t + 2) : (TT - 1);
#pragma unroll
    for (int kc = 0; kc < 4; ++kc) {
      emQa[S][kc] = emLa[(size_t)tp * 1024 + kc];
      emQb[S][kc] = emLb[(size_t)tp * 1024 + kc];
    }
  }

  float na[8][4], nb[8][4];
#pragma unroll
  for (int jt = 0; jt < 8; ++jt) {
    uint4 wa = eva[jt >> 1];
    unsigned a0 = (jt & 1) ? wa.z : wa.x;
    unsigned a1 = (jt & 1) ? wa.w : wa.y;
    na[jt][0] = acca[jt][0] * bflo(a0);
    na[jt][1] = acca[jt][1] * bfhi(a0);
    na[jt][2] = acca[jt][2] * bflo(a1);
    na[jt][3] = acca[jt][3] * bfhi(a1);
    uint4 wb = evb[jt >> 1];
    unsigned b0 = (jt & 1) ? wb.z : wb.x;
    unsigned b1 = (jt & 1) ? wb.w : wb.y;
    nb[jt][0] = accb[jt][0] * bflo(b0);
    nb[jt][1] = accb[jt][1] * bfhi(b0);
    nb[jt][2] = accb[jt][2] * bflo(b1);
    nb[jt][3] = accb[jt][3] * bfhi(b1);
  }

  if ((t & 63) == 0) {  // true normalize to sum=128 (alpha mean 1.0)
    float sa = 0.f, sb = 0.f;
#pragma unroll
    for (int jt = 0; jt < 8; ++jt) {
      sa += (na[jt][0] + na[jt][1]) + (na[jt][2] + na[jt][3]);
      sb += (nb[jt][0] + nb[jt][1]) + (nb[jt][2] + nb[jt][3]);
    }
    sa += __shfl_xor(sa, 16, 64); sa += __shfl_xor(sa, 32, 64);
    sb += __shfl_xor(sb, 16, 64); sb += __shfl_xor(sb, 32, 64);
    float pa = sa * 0.0078125f, pb = sb * 0.0078125f;
    float ra = __builtin_amdgcn_rcpf(pa);
    float rb = __builtin_amdgcn_rcpf(pb);
    La += __logf(pa);
    Lb += __logf(pb);
#pragma unroll
    for (int jt = 0; jt < 8; ++jt) {
      na[jt][0] *= ra; na[jt][1] *= ra; na[jt][2] *= ra; na[jt][3] *= ra;
      nb[jt][0] *= rb; nb[jt][1] *= rb; nb[jt][2] *= rb; nb[jt][3] *= rb;
    }
  }

  if (LAST) {
#pragma unroll
    for (int jt = 0; jt < 8; ++jt)
#pragma unroll
      for (int r = 0; r < 4; ++r) { nfa[jt][r] = na[jt][r]; nfb[jt][r] = nb[jt][r]; }
    return;
  }

#pragma unroll
  for (int jt = 0; jt < 8; ++jt) {
    int wa = __builtin_amdgcn_cvt_pk_fp8_f32(na[jt][0], na[jt][1], 0, false);
    wa = __builtin_amdgcn_cvt_pk_fp8_f32(na[jt][2], na[jt][3], wa, true);
    bfa[jt] = wa;
    int wb = __builtin_amdgcn_cvt_pk_fp8_f32(nb[jt][0], nb[jt][1], 0, false);
    wb = __builtin_amdgcn_cvt_pk_fp8_f32(nb[jt][2], nb[jt][3], wb, true);
    bfb[jt] = wb;
  }
}

__global__ __launch_bounds__(64, 1)
void k_fwd_m5(const unsigned* __restrict__ em, const float* __restrict__ A2p,
              const float* __restrict__ piZP, float* __restrict__ ll, int V) {
  const int l = threadIdx.x;
  const int m = l & 15;
  const int g = l >> 4;
  const int gbA = blockIdx.x * 32 + m;
  const int gbB = blockIdx.x * 32 + 16 + m;

  // static A fragments: 8 x v8i = 64 regs of fp8 (shared by both chains)
  v8i af[8];
#pragma unroll
  for (int jt = 0; jt < 8; ++jt) {
    const int colj = 16 * jt + m;
#pragma unroll
    for (int w = 0; w < 8; ++w) {
      const float* ap = A2p + (size_t)(16 * w + 4 * g) * KK + colj;
      int ww = __builtin_amdgcn_cvt_pk_fp8_f32(ap[0], ap[KK], 0, false);
      ww = __builtin_amdgcn_cvt_pk_fp8_f32(ap[2 * KK], ap[3 * KK], ww, true);
      af[jt][w] = ww;
    }
  }

  const uint4* emLa = (const uint4*)(em + (size_t)gbA * 64 + 16 * g);
  const uint4* emLb = (const uint4*)(em + (size_t)gbB * 64 + 16 * g);
  float La = 0.f, Lb = 0.f;

  // alpha0 = piZP * em0 -> initial B operands (fp8), both chains
  v8i bfa, bfb;
  {
#pragma unroll
    for (int jt = 0; jt < 8; ++jt) {
      float4 pz = *(const float4*)(piZP + 32 * g + 4 * jt);
      uint4 wa = emLa[jt >> 1];
      unsigned a0 = (jt & 1) ? wa.z : wa.x;
      unsigned a1 = (jt & 1) ? wa.w : wa.y;
      int ww = __builtin_amdgcn_cvt_pk_fp8_f32(pz.x * bflo(a0), pz.y * bfhi(a0), 0, false);
      ww = __builtin_amdgcn_cvt_pk_fp8_f32(pz.z * bflo(a1), pz.w * bfhi(a1), ww, true);
      bfa[jt] = ww;
      uint4 wb = emLb[jt >> 1];
      unsigned b0 = (jt & 1) ? wb.z : wb.x;
      unsigned b1 = (jt & 1) ? wb.w : wb.y;
      int wv = __builtin_amdgcn_cvt_pk_fp8_f32(pz.x * bflo(b0), pz.y * bfhi(b0), 0, false);
      wv = __builtin_amdgcn_cvt_pk_fp8_f32(pz.z * bflo(b1), pz.w * bfhi(b1), wv, true);
      bfb[jt] = wv;
    }
  }

  // em prefetch, depth 2 (slot = t&1): preload t=1 (slot1), t=2 (slot0)
  uint4 emQa[2][4], emQb[2][4];
#pragma unroll
  for (int tp = 1; tp <= 2; ++tp)
#pragma unroll
    for (int kc = 0; kc < 4; ++kc) {
      emQa[tp & 1][kc] = emLa[(size_t)tp * 1024 + kc];
      emQb[tp & 1][kc] = emLb[(size_t)tp * 1024 + kc];
    }

  float nfa[8][4], nfb[8][4];
  // t = 1..2046 in pairs (S = t&1), then LAST t=2047 (S=1)
  for (int c = 0; c < (TT - 2) / 2; ++c) {
    const int t0 = 1 + 2 * c;
    step8d<1, false>(t0 + 0, emLa, emLb, af, bfa, bfb, emQa, emQb, La, Lb, nfa, nfb);
    step8d<0, false>(t0 + 1, emLa, emLb, af, bfa, bfb, emQa, emQb, La, Lb, nfa, nfb);
  }
  step8d<1, true>(TT - 1, emLa, emLb, af, bfa, bfb, emQa, emQb, La, Lb, nfa, nfb);

  float sa = 0.f, sb = 0.f;
#pragma unroll
  for (int jt = 0; jt < 8; ++jt) {
    sa += (nfa[jt][0] + nfa[jt][1]) + (nfa[jt][2] + nfa[jt][3]);
    sb += (nfb[jt][0] + nfb[jt][1]) + (nfb[jt][2] + nfb[jt][3]);
  }
  sa += __shfl_xor(sa, 16, 64); sa += __shfl_xor(sa, 32, 64);
  sb += __shfl_xor(sb, 16, 64); sb += __shfl_xor(sb, 32, 64);
  // folds: x(V/Z) per t (2048 log V total), init x128.
  const float RESCALE_C = (float)((double)TT * log((double)V) + log(128.0));
  if (l < 16) {
    ll[blockIdx.x * 32 + l]      = La + __logf(sa) - RESCALE_C;
    ll[blockIdx.x * 32 + 16 + l] = Lb + __logf(sb) - RESCALE_C;
  }
}

// ---------------- K4-fallback (round-3 path, used if ws too small) --------
__global__ __launch_bounds__(256, 1)
void k_fwd_fb(const int* __restrict__ toks, const float* __restrict__ E,
              const float* __restrict__ A2, const float* __restrict__ piZ,
              float* __restrict__ ll) {
  __shared__ float pb[2][KK];
  __shared__ float part[2 * KK];
  __shared__ int tk[TT];
  __shared__ float red[4];
  const int tid = threadIdx.x;
  const int j = tid & (KK - 1);
  const int h = tid >> 7;
  const int b = blockIdx.x;

  const int4* t4 = (const int4*)(toks + (size_t)b * TT);
  int4* l4 = (int4*)tk;
#pragma unroll
  for (int c = 0; c < TT / 4 / 256; ++c) l4[c * 256 + tid] = t4[c * 256 + tid];

  float Areg[64];
  {
    const float* Acol = A2 + (size_t)(h * 64) * KK + j;
#pragma unroll
    for (int i = 0; i < 64; ++i) Areg[i] = Acol[i * KK];
  }
  __syncthreads();

  const float* Ej = E + j;
  float eA = Ej[(size_t)tk[1] * KK];
  float eB = Ej[(size_t)tk[2] * KK];
  float eC = Ej[(size_t)tk[3] * KK];
  float eD = Ej[(size_t)tk[4] * KK];
  if (h == 0) pb[0][j] = piZ[j] * Ej[(size_t)tk[0] * KK];
  float Lacc = 0.f;
  __syncthreads();

  for (int t = 1; t < TT; ++t) {
    const float4* ph = (const float4*)&pb[(t - 1) & 1][h * 64];
    float a0 = 0.f, a1 = 0.f, a2 = 0.f, a3 = 0.f;
#pragma unroll
    for (int c = 0; c < 16; ++c) {
      float4 pv = ph[c];
      a0 = fmaf(pv.x, Areg[4 * c + 0], a0);
      a1 = fmaf(pv.y, Areg[4 * c + 1], a1);
      a2 = fmaf(pv.z, Areg[4 * c + 2], a2);
      a3 = fmaf(pv.w, Areg[4 * c + 3], a3);
    }
    part[2 * j + h] = (a0 + a1) + (a2 + a3);
    __syncthreads();

    float e = eA; eA = eB; eB = eC; eC = eD;
    int tn = tk[t + 4 < TT ? t + 4 : TT - 1];
    eD = Ej[(size_t)tn * KK];

    float np = 0.f;
    if (h == 0) {
      float2 pr = *(const float2*)&part[2 * j];
      np = (pr.x + pr.y) * e;
    }
    if ((t & 63) == 0) {
      float v = wave_sum64(np);
      if ((tid & 63) == 0) red[tid >> 6] = v;
      __syncthreads();
      float tot = (red[0] + red[1]) + (red[2] + red[3]);
      np *= __builtin_amdgcn_rcpf(tot);
      if (tid == 0) Lacc += __logf(tot);
    } else if ((t & 3) == 0) {
      np *= 0x1p64f;
    }
    if (h == 0) pb[t & 1][j] = np;
    __syncthreads();
  }

  float lv = (h == 0) ? pb[(TT - 1) & 1][j] : 0.f;
  float v = wave_sum64(lv);
  if ((tid & 63) == 0) red[tid >> 6] = v;
  __syncthreads();
  float tot = (red[0] + red[1]) + (red[2] + red[3]);
  const float RESCALE_C = (float)(30720.0 * 0.6931471805599453);
  if (tid == 0) ll[b] = Lacc + __logf(tot) - RESCALE_C;
}

// ---------------- K5: final reduction ----------------
__global__ void k_final(const float* __restrict__ ll, float* __restrict__ out) {
  float v = ll[threadIdx.x];
  v = wave_sum64(v);
  if (threadIdx.x == 0) out[0] = -v;
}

extern "C" void kernel_launch(void* const* d_in, const int* in_sizes, int n_in,
                              void* d_out, int out_size, void* d_ws, size_t ws_size,
                              hipStream_t stream) {
  const int*   toks    = (const int*)d_in[0];
  const float* initlog = (const float*)d_in[1];
  const float* tag     = (const float*)d_in[2];
  const float* word    = (const float*)d_in[3];
  const float* bias    = (const float*)d_in[4];
  const float* q       = (const float*)d_in[5];
  const float* W       = (const float*)d_in[6];
  const float* tb      = (const float*)d_in[7];
  float* out = (float*)d_out;

  const int V = in_sizes[4];
  const int nPart = (V + 127) / 128;

  float* ws    = (float*)d_ws;
  float* E     = ws;
  float* pZ    = E + (size_t)V * KK;
  float* A2    = pZ + (size_t)nPart * KK;
  float* A2p   = A2 + KK * KK;
  float* piZ   = A2p + KK * KK;
  float* piZP  = piZ + KK;
  float* ZinvP = piZP + KK;
  float* ll    = ZinvP + KK;
  unsigned* em = (unsigned*)(ll + BB);  // TT*BB*64 u32 = 32 MB

  const size_t floats_before_em =
      (size_t)V * KK + (size_t)nPart * KK + 2 * KK * KK + 3 * KK + BB;
  const size_t need = floats_before_em * 4 + (size_t)TT * BB * 64 * 4;

  k_emis <<<nPart, 128, 0, stream>>>(tag, word, bias, E, pZ, V);
  k_trans<<<KK, 128, 0, stream>>>(W, q, tb, pZ, initlog, A2, A2p, piZ, piZP,
                                  ZinvP, nPart, V);
  if (ws_size >= need) {
    k_gather<<<dim3(BB, TT / 32), 128, 0, stream>>>(toks, E, ZinvP, em);
    k_fwd_m5<<<2, 64, 0, stream>>>(em, A2p, piZP, ll, V);
  } else {
    k_fwd_fb<<<BB, 256, 0, stream>>>(toks, E, A2, piZ, ll);
  }
  k_final<<<1, BB, 0, stream>>>(ll, out);
}

// Round 9
// 439.084 us; speedup vs baseline: 3.5618x; 3.5618x over previous
//
#include <hip/hip_runtime.h>

// Neural HMM forward-algorithm NLL.  K=128, V=50257, D=H=128, B=64, T=2048.
//
// r5-r8 measured: a single in-order wave gets ZERO overlap (wall = sum of
// per-instruction blocking; dual-chain scaled linearly twice). With only 4
// recursion chains the old structure is pinned to 1 wave/SIMD on 4 SIMDs.
// Fix: associative scan. alpha_t = alpha_{t-1} M_t (M_t = A diag(e_t)) ->
// 32 segments x 64 batches = 2048 independent chains, each propagating a
// 128x128 matrix Q <- diag(e_t) A^T Q (t ascending) via MX-FP8 MFMA.
// 128x more FLOPs (550 GFLOP) but full-chip MFMA occupancy (2 waves/SIMD).
//
//  K1 k_emis : E128[v][k] = bf16(128*exp(tag_k . word_v + bias_v)) + partial Z
//  K2 k_trans: A2 (Z-folded, fb), A2p = 128*softmax rows, piZ (fb),
//              piPlain = softmax(init), Zinv[j] = V/Z_j
//  K3 k_scan : per (seg,batch): Q init I*128 (fp8), 64 steps of
//              Qstored <- 128 * diag(E*V/Z) A^T Qtrue  (stored = true*128
//              invariant; SA=SB=2^-7 cancels the two x128 of the operands,
//              E128's x128 is the repack scale; zi folded into af columns).
//              Byte/lane layout identical to r7's HW-verified kernel.
//  K4 k_comb : per batch: alpha <- Q_s alpha (s ascending), fp8 LUT decode,
//              x2^-7 per segment keeps stored = true*128.
//              LL_b = log(sum/128) - 2048*log(V).
//  K5 k_final: out = -sum_b ll[b]

#define KK 128
#define TT 2048
#define BB 64
#define NSEG 32
#define SEGLEN 64

typedef int v8i __attribute__((ext_vector_type(8)));
typedef float v4f __attribute__((ext_vector_type(4)));

__device__ __forceinline__ float wave_sum64(float v) {
#pragma unroll
  for (int m = 32; m; m >>= 1) v += __shfl_xor(v, m, 64);
  return v;
}
__device__ __forceinline__ float wave_max64(float v) {
#pragma unroll
  for (int m = 32; m; m >>= 1) v = fmaxf(v, __shfl_xor(v, m, 64));
  return v;
}
// f32 -> bf16 round-to-nearest-even (positive normals here)
__device__ __forceinline__ unsigned short f2bf(float x) {
  union { float f; unsigned u; } c; c.f = x;
  unsigned r = c.u + 0x7fffu + ((c.u >> 16) & 1u);
  return (unsigned short)(r >> 16);
}
__device__ __forceinline__ float bflo(unsigned u) {
  union { unsigned u; float f; } c; c.u = u << 16; return c.f;
}
__device__ __forceinline__ float bfhi(unsigned u) {
  union { unsigned u; float f; } c; c.u = u & 0xffff0000u; return c.f;
}

// ---------------- K1: emission table E128 (V x K, bf16 of 128*e) ----------
__global__ __launch_bounds__(128, 1)
void k_emis(const float* __restrict__ tag, const float* __restrict__ word,
            const float* __restrict__ bias, unsigned short* __restrict__ E128,
            float* __restrict__ partialZ, int V) {
  __shared__ float4 wtile[128 * 32];
  __shared__ float btile[128];
  const int tid = threadIdx.x;
  const int v0 = blockIdx.x * 128;

  const float4* w4 = (const float4*)word;
  const int maxi = V * 32 - 1;
#pragma unroll
  for (int it = 0; it < 32; ++it) {
    int idx = it * 128 + tid;
    int g = v0 * 32 + idx;
    wtile[idx] = w4[min(g, maxi)];
  }
  btile[tid] = (v0 + tid < V) ? bias[v0 + tid] : 0.f;

  float treg[128];
  const float4* t4 = (const float4*)(tag + (size_t)tid * 128);
#pragma unroll
  for (int c = 0; c < 32; ++c) {
    float4 x = t4[c];
    treg[4 * c + 0] = x.x; treg[4 * c + 1] = x.y;
    treg[4 * c + 2] = x.z; treg[4 * c + 3] = x.w;
  }
  __syncthreads();

  float zp = 0.f;
  for (int v = 0; v < 128; ++v) {
    if (v0 + v >= V) break;  // uniform
    const float4* row = &wtile[v * 32];
    float a0 = 0.f, a1 = 0.f, a2 = 0.f, a3 = 0.f;
#pragma unroll
    for (int c = 0; c < 32; ++c) {
      float4 pv = row[c];
      a0 = fmaf(pv.x, treg[4 * c + 0], a0);
      a1 = fmaf(pv.y, treg[4 * c + 1], a1);
      a2 = fmaf(pv.z, treg[4 * c + 2], a2);
      a3 = fmaf(pv.w, treg[4 * c + 3], a3);
    }
    float e = __expf((a0 + a1) + (a2 + a3) + btile[v]);
    E128[(size_t)(v0 + v) * KK + tid] = f2bf(128.f * e);
    zp += e;
  }
  partialZ[(size_t)blockIdx.x * KK + tid] = zp;
}

// ---------------- K2: transition matrix + piZ/piPlain/Zinv/A2p ------------
__global__ __launch_bounds__(128)
void k_trans(const float* __restrict__ W, const float* __restrict__ q,
             const float* __restrict__ tb, const float* __restrict__ pZ,
             const float* __restrict__ initlog, float* __restrict__ A2,
             float* __restrict__ A2p, float* __restrict__ piZ,
             float* __restrict__ piPlain, float* __restrict__ Zinv,
             int nPart, int V) {
  __shared__ float qs[KK];
  __shared__ float r0[2], r1[2];
  const int j = threadIdx.x, i = blockIdx.x;
  qs[j] = q[j];
  __syncthreads();

  const float4* w4 = (const float4*)(W + ((size_t)(i * KK + j)) * KK);
  const float4* q4 = (const float4*)qs;
  float a0 = 0.f, a1 = 0.f, a2 = 0.f, a3 = 0.f;
#pragma unroll
  for (int c = 0; c < KK / 4; ++c) {
    float4 wv = w4[c], qv = q4[c];
    a0 = fmaf(wv.x, qv.x, a0); a1 = fmaf(wv.y, qv.y, a1);
    a2 = fmaf(wv.z, qv.z, a2); a3 = fmaf(wv.w, qv.w, a3);
  }
  float logit = (a0 + a1) + (a2 + a3) + tb[i * KK + j];

  float m = wave_max64(logit);
  if ((j & 63) == 0) r0[j >> 6] = m;
  __syncthreads();
  m = fmaxf(r0[0], r0[1]);
  float e = __expf(logit - m);
  float s = wave_sum64(e);
  if ((j & 63) == 0) r1[j >> 6] = s;
  __syncthreads();
  s = r1[0] + r1[1];

  float Z0 = 0.f, Z1 = 0.f, Z2 = 0.f, Z3 = 0.f;
  float Z4 = 0.f, Z5 = 0.f, Z6 = 0.f, Z7 = 0.f;
  int p = 0;
  for (; p + 8 <= nPart; p += 8) {
    Z0 += pZ[(size_t)(p + 0) * KK + j]; Z1 += pZ[(size_t)(p + 1) * KK + j];
    Z2 += pZ[(size_t)(p + 2) * KK + j]; Z3 += pZ[(size_t)(p + 3) * KK + j];
    Z4 += pZ[(size_t)(p + 4) * KK + j]; Z5 += pZ[(size_t)(p + 5) * KK + j];
    Z6 += pZ[(size_t)(p + 6) * KK + j]; Z7 += pZ[(size_t)(p + 7) * KK + j];
  }
  for (; p < nPart; ++p) Z0 += pZ[(size_t)p * KK + j];
  float Z = ((Z0 + Z1) + (Z2 + Z3)) + ((Z4 + Z5) + (Z6 + Z7));

  A2[i * KK + j] = e / (s * Z);        // fallback path (Z-folded)
  A2p[i * KK + j] = 128.0f * e / s;    // scan path: pure softmax x128 (~1.0)

  if (i == 0) {
    float x = initlog[j];
    __syncthreads();
    float m2 = wave_max64(x);
    if ((j & 63) == 0) r0[j >> 6] = m2;
    __syncthreads();
    m2 = fmaxf(r0[0], r0[1]);
    float e2 = __expf(x - m2);
    float s2 = wave_sum64(e2);
    if ((j & 63) == 0) r1[j >> 6] = s2;
    __syncthreads();
    s2 = r1[0] + r1[1];
    piZ[j] = e2 / (s2 * Z);
    piPlain[j] = e2 / s2;
    Zinv[j] = (float)V / Z;
  }
}

// ---------------- K3: segmented matrix scan (MX-FP8) ----------------------
// 2048 blocks x 64 thr (1 wave). chain = s*64+b. lane: m = l&15, g = l>>4.
// Byte/lane maps identical to r7's verified kernel:
//   af[it] word w byte c : A2p[16w+4g+c][16it+m] * Zinv[16it+m]   (A-operand)
//   Q[jt]  word w byte c : Qstored[row 16w+4g+c][col 16jt+m]      (B-operand)
//   D(it,jt) lane reg r  -> row 16it+4g+r, col 16jt+m  -> Q[jt] word it.
// Step: Qstored <- 128*( diag(E*zi) A^T Qtrue );  SA=SB=2^-7; e = E128 row.
__device__ __forceinline__ void scan_step(
    int n, int nst, const int* __restrict__ tks,
    const unsigned short* __restrict__ E128, const v8i (&af)[8], v8i (&Q)[8],
    uint2 (&evU)[8], uint2 (&evL)[8], int g) {
  // prefetch next step's e-row (consumed ~one full step later)
  int np = (n + 1 < nst) ? n + 1 : nst - 1;
  const unsigned short* ern = E128 + (size_t)tks[np] * KK;
#pragma unroll
  for (int it = 0; it < 8; ++it)
    evL[it] = *(const uint2*)(ern + 16 * it + 4 * g);

  const v4f ZED = {0.f, 0.f, 0.f, 0.f};
#pragma unroll
  for (int jt = 0; jt < 8; ++jt) {
    v4f acc[8];
#pragma unroll
    for (int it = 0; it < 8; ++it)
      acc[it] = __builtin_amdgcn_mfma_scale_f32_16x16x128_f8f6f4(
          af[it], Q[jt], ZED, 0, 0, 0, 0x78787878, 0, 0x78787878);
#pragma unroll
    for (int it = 0; it < 8; ++it) {
      float e0 = bflo(evU[it].x), e1 = bfhi(evU[it].x);
      float e2 = bflo(evU[it].y), e3 = bfhi(evU[it].y);
      int w = __builtin_amdgcn_cvt_pk_fp8_f32(acc[it][0] * e0, acc[it][1] * e1, 0, false);
      w = __builtin_amdgcn_cvt_pk_fp8_f32(acc[it][2] * e2, acc[it][3] * e3, w, true);
      Q[jt][it] = w;
    }
  }
}

__global__ __launch_bounds__(64, 2)
void k_scan(const int* __restrict__ toks, const unsigned short* __restrict__ E128,
            const float* __restrict__ A2p, const float* __restrict__ Zinv,
            uint4* __restrict__ P) {
  __shared__ int tks[SEGLEN];
  const int chain = blockIdx.x;
  const int s = chain >> 6;
  const int b = chain & 63;
  const int l = threadIdx.x, m = l & 15, g = l >> 4;
  const int t0 = SEGLEN * s + 1;
  const int nst = (s == NSEG - 1) ? SEGLEN - 1 : SEGLEN;  // t <= 2047
  if (l < nst) tks[l] = toks[(size_t)b * TT + t0 + l];

  // static A-operand: Ã = A2p with Zinv folded into output columns
  v8i af[8];
#pragma unroll
  for (int it = 0; it < 8; ++it) {
    const int colj = 16 * it + m;
    const float zj = Zinv[colj];
#pragma unroll
    for (int w = 0; w < 8; ++w) {
      const float* ap = A2p + (size_t)(16 * w + 4 * g) * KK + colj;
      int ww = __builtin_amdgcn_cvt_pk_fp8_f32(ap[0] * zj, ap[KK] * zj, 0, false);
      ww = __builtin_amdgcn_cvt_pk_fp8_f32(ap[2 * KK] * zj, ap[3 * KK] * zj, ww, true);
      af[it][w] = ww;
    }
  }

  // Q = 128 * Identity (fp8 0x70 = 128.0 at row==col)
  v8i Q[8];
  const unsigned diag = (g == (m >> 2)) ? (0x70u << (8 * (m & 3))) : 0u;
#pragma unroll
  for (int jt = 0; jt < 8; ++jt) {
#pragma unroll
    for (int w = 0; w < 8; ++w) Q[jt][w] = (w == jt) ? (int)diag : 0;
  }

  __syncthreads();

  uint2 evA[8], evB[8];
  {
    const unsigned short* er0 = E128 + (size_t)tks[0] * KK;
#pragma unroll
    for (int it = 0; it < 8; ++it) evA[it] = *(const uint2*)(er0 + 16 * it + 4 * g);
  }
  const int pairs = nst >> 1;
  for (int c = 0; c < pairs; ++c) {
    scan_step(2 * c + 0, nst, tks, E128, af, Q, evA, evB, g);
    scan_step(2 * c + 1, nst, tks, E128, af, Q, evB, evA, g);
  }
  if (nst & 1) scan_step(nst - 1, nst, tks, E128, af, Q, evA, evB, g);

  // dump Q (per-lane natural order; combine uses the same indexing)
  uint4* base = P + (size_t)chain * 1024;
#pragma unroll
  for (int jt = 0; jt < 8; ++jt) {
    union { v8i v; uint4 u[2]; } x; x.v = Q[jt];
    base[jt * 128 + l * 2 + 0] = x.u[0];
    base[jt * 128 + l * 2 + 1] = x.u[1];
  }
}

// ---------------- K4: combine segments per batch ---------------------------
// alpha^T <- Q_s alpha^T, s = 0..31. Lane (m,g) owns cols {16jt+m}; its bytes
// cover rows {16w+4g+c}; reduce partial row-sums over the 16 m-lanes.
__global__ __launch_bounds__(64, 1)
void k_comb(const uint4* __restrict__ P, const float* __restrict__ piPlain,
            const unsigned short* __restrict__ E128, const float* __restrict__ Zinv,
            const int* __restrict__ toks, float* __restrict__ ll, int V) {
  __shared__ float alpha[KK];
  __shared__ float lut[256];
  const int b = blockIdx.x;
  const int l = threadIdx.x, m = l & 15, g = l >> 4;

  // e4m3fn decode LUT (bias 7, denormals m*2^-9)
  for (int i = l; i < 256; i += 64) {
    int ex = (i >> 3) & 15, mt = i & 7;
    float v = (ex == 0) ? ldexpf((float)mt, -9)
                        : ldexpf(1.f + (float)mt * 0.125f, ex - 7);
    lut[i] = (i & 0x80) ? -v : v;
  }
  {  // alpha_1 = pi * E*zi  (stored = true*128 via E128's x128)
    int tok0 = toks[(size_t)b * TT];
    for (int j = l; j < KK; j += 64)
      alpha[j] = piPlain[j] * bflo((unsigned)E128[(size_t)tok0 * KK + j]) * Zinv[j];
  }
  __syncthreads();

  for (int s = 0; s < NSEG; ++s) {
    const uint4* base = P + ((size_t)(s * 64 + b)) * 1024;
    float ac[8];
#pragma unroll
    for (int jt = 0; jt < 8; ++jt) ac[jt] = alpha[16 * jt + m];
    float out[32];
#pragma unroll
    for (int k = 0; k < 32; ++k) out[k] = 0.f;
#pragma unroll
    for (int jt = 0; jt < 8; ++jt) {
      uint4 qa = base[jt * 128 + l * 2 + 0];
      uint4 qb = base[jt * 128 + l * 2 + 1];
      const float aj = ac[jt];
      unsigned wds[8] = {qa.x, qa.y, qa.z, qa.w, qb.x, qb.y, qb.z, qb.w};
#pragma unroll
      for (int w = 0; w < 8; ++w) {
#pragma unroll
        for (int c = 0; c < 4; ++c) {
          float v = lut[(wds[w] >> (8 * c)) & 0xffu];
          out[w * 4 + c] = fmaf(v, aj, out[w * 4 + c]);
        }
      }
    }
    __syncthreads();  // all alpha reads done before overwrite
#pragma unroll
    for (int k = 0; k < 32; ++k) {
      out[k] += __shfl_xor(out[k], 1, 64);
      out[k] += __shfl_xor(out[k], 2, 64);
      out[k] += __shfl_xor(out[k], 4, 64);
      out[k] += __shfl_xor(out[k], 8, 64);
    }
    if (m == 0) {
#pragma unroll
      for (int w = 0; w < 8; ++w)
#pragma unroll
        for (int c = 0; c < 4; ++c)
          alpha[16 * w + 4 * g + c] = out[w * 4 + c] * 0.0078125f;  // keep x128
    }
    __syncthreads();
  }

  float sm = alpha[l] + alpha[l + 64];
  sm = wave_sum64(sm);
  // stored = true*128; zi folded V once per em-application (2048 total)
  const float C = (float)(log(128.0) + (double)TT * log((double)V));
  if (l == 0) ll[b] = __logf(sm) - C;
}

// ---------------- fallback (round-3 path; E now bf16 x128) ----------------
__global__ __launch_bounds__(256, 1)
void k_fwd_fb(const int* __restrict__ toks, const unsigned short* __restrict__ E128,
              const float* __restrict__ A2, const float* __restrict__ piZ,
              float* __restrict__ ll) {
  __shared__ float pb[2][KK];
  __shared__ float part[2 * KK];
  __shared__ int tk[TT];
  __shared__ float red[4];
  const int tid = threadIdx.x;
  const int j = tid & (KK - 1);
  const int h = tid >> 7;
  const int b = blockIdx.x;

  const int4* t4 = (const int4*)(toks + (size_t)b * TT);
  int4* l4 = (int4*)tk;
#pragma unroll
  for (int c = 0; c < TT / 4 / 256; ++c) l4[c * 256 + tid] = t4[c * 256 + tid];

  float Areg[64];
  {
    const float* Acol = A2 + (size_t)(h * 64) * KK + j;
#pragma unroll
    for (int i = 0; i < 64; ++i) Areg[i] = Acol[i * KK];
  }
  __syncthreads();

  const unsigned short* Ej = E128 + j;
  const float inv128 = 0.0078125f;
  float eA = inv128 * bflo((unsigned)Ej[(size_t)tk[1] * KK]);
  float eB = inv128 * bflo((unsigned)Ej[(size_t)tk[2] * KK]);
  float eC = inv128 * bflo((unsigned)Ej[(size_t)tk[3] * KK]);
  float eD = inv128 * bflo((unsigned)Ej[(size_t)tk[4] * KK]);
  if (h == 0) pb[0][j] = piZ[j] * inv128 * bflo((unsigned)Ej[(size_t)tk[0] * KK]);
  float Lacc = 0.f;
  __syncthreads();

  for (int t = 1; t < TT; ++t) {
    const float4* ph = (const float4*)&pb[(t - 1) & 1][h * 64];
    float a0 = 0.f, a1 = 0.f, a2 = 0.f, a3 = 0.f;
#pragma unroll
    for (int c = 0; c < 16; ++c) {
      float4 pv = ph[c];
      a0 = fmaf(pv.x, Areg[4 * c + 0], a0);
      a1 = fmaf(pv.y, Areg[4 * c + 1], a1);
      a2 = fmaf(pv.z, Areg[4 * c + 2], a2);
      a3 = fmaf(pv.w, Areg[4 * c + 3], a3);
    }
    part[2 * j + h] = (a0 + a1) + (a2 + a3);
    __syncthreads();

    float e = eA; eA = eB; eB = eC; eC = eD;
    int tn = tk[t + 4 < TT ? t + 4 : TT - 1];
    eD = inv128 * bflo((unsigned)Ej[(size_t)tn * KK]);

    float np = 0.f;
    if (h == 0) {
      float2 pr = *(const float2*)&part[2 * j];
      np = (pr.x + pr.y) * e;
    }
    if ((t & 63) == 0) {
      float v = wave_sum64(np);
      if ((tid & 63) == 0) red[tid >> 6] = v;
      __syncthreads();
      float tot = (red[0] + red[1]) + (red[2] + red[3]);
      np *= __builtin_amdgcn_rcpf(tot);
      if (tid == 0) Lacc += __logf(tot);
    } else if ((t & 3) == 0) {
      np *= 0x1p64f;
    }
    if (h == 0) pb[t & 1][j] = np;
    __syncthreads();
  }

  float lv = (h == 0) ? pb[(TT - 1) & 1][j] : 0.f;
  float v = wave_sum64(lv);
  if ((tid & 63) == 0) red[tid >> 6] = v;
  __syncthreads();
  float tot = (red[0] + red[1]) + (red[2] + red[3]);
  const float RESCALE_C = (float)(30720.0 * 0.6931471805599453);
  if (tid == 0) ll[b] = Lacc + __logf(tot) - RESCALE_C;
}

// ---------------- K5: final reduction ----------------
__global__ void k_final(const float* __restrict__ ll, float* __restrict__ out) {
  float v = ll[threadIdx.x];
  v = wave_sum64(v);
  if (threadIdx.x == 0) out[0] = -v;
}

extern "C" void kernel_launch(void* const* d_in, const int* in_sizes, int n_in,
                              void* d_out, int out_size, void* d_ws, size_t ws_size,
                              hipStream_t stream) {
  const int*   toks    = (const int*)d_in[0];
  const float* initlog = (const float*)d_in[1];
  const float* tag     = (const float*)d_in[2];
  const float* word    = (const float*)d_in[3];
  const float* bias    = (const float*)d_in[4];
  const float* q       = (const float*)d_in[5];
  const float* W       = (const float*)d_in[6];
  const float* tb      = (const float*)d_in[7];
  float* out = (float*)d_out;

  const int V = in_sizes[4];
  const int nPart = (V + 127) / 128;

  unsigned short* E128 = (unsigned short*)d_ws;        // V*128 bf16
  float* pZ      = (float*)(E128 + (size_t)V * KK);    // nPart*128
  float* A2      = pZ + (size_t)nPart * KK;            // 128^2 (fb)
  float* A2p     = A2 + KK * KK;                       // 128^2
  float* piZ     = A2p + KK * KK;                      // 128 (fb)
  float* piPlain = piZ + KK;                           // 128
  float* Zinv    = piPlain + KK;                       // 128
  float* ll      = Zinv + KK;                          // 64
  uintptr_t pp = (uintptr_t)(ll + BB);
  pp = (pp + 15) & ~(uintptr_t)15;
  uint4* P = (uint4*)pp;                               // 2048 * 16 KB = 33.5 MB

  const size_t need =
      (pp - (uintptr_t)d_ws) + (size_t)NSEG * BB * 1024 * sizeof(uint4);

  k_emis <<<nPart, 128, 0, stream>>>(tag, word, bias, E128, pZ, V);
  k_trans<<<KK, 128, 0, stream>>>(W, q, tb, pZ, initlog, A2, A2p, piZ,
                                  piPlain, Zinv, nPart, V);
  if (ws_size >= need) {
    k_scan<<<NSEG * BB, 64, 0, stream>>>(toks, E128, A2p, Zinv, P);
    k_comb<<<BB, 64, 0, stream>>>(P, piPlain, E128, Zinv, toks, ll, V);
  } else {
    k_fwd_fb<<<BB, 256, 0, stream>>>(toks, E128, A2, piZ, ll);
  }
  k_final<<<1, BB, 0, stream>>>(ll, out);
}